// Round 4
// baseline (1939.535 us; speedup 1.0000x reference)
//
#include <hip/hip_runtime.h>
#include <hip/hip_bf16.h>
#include <hip/hip_fp16.h>
#include <stdint.h>

#define CCH 128  // channels
#define FINAL_SCALE 268435456.0f  // 16^7: undo 7 steps of 1/16 scaling (step 8 unscaled)

// ---------------- CSR build ----------------

__global__ void hist_kernel(const int* __restrict__ rows, int* __restrict__ counts, int E) {
    int stride = gridDim.x * blockDim.x;
    for (int e = blockIdx.x * blockDim.x + threadIdx.x; e < E; e += stride)
        atomicAdd(&counts[rows[e]], 1);
}

// Phase A: per-block (1024) inclusive scan -> row_ptr[i+1] (tile-local), block sum -> partials
__global__ __launch_bounds__(1024) void scanA_kernel(const int* __restrict__ counts,
                                                     int* __restrict__ row_ptr,
                                                     int* __restrict__ partials, int n) {
    __shared__ int tile[1024];
    int t = threadIdx.x;
    int i = blockIdx.x * 1024 + t;
    tile[t] = (i < n) ? counts[i] : 0;
    __syncthreads();
    for (int off = 1; off < 1024; off <<= 1) {
        int add = (t >= off) ? tile[t - off] : 0;
        __syncthreads();
        tile[t] += add;
        __syncthreads();
    }
    if (i < n) row_ptr[i + 1] = tile[t];
    if (t == 1023) partials[blockIdx.x] = tile[1023];
}

// Phase B: single block scans partials (nb <= 1024) in place -> exclusive offsets
__global__ __launch_bounds__(1024) void scanB_kernel(int* __restrict__ partials,
                                                     int* __restrict__ row_ptr, int nb) {
    __shared__ int tile[1024];
    int t = threadIdx.x;
    tile[t] = (t < nb) ? partials[t] : 0;
    __syncthreads();
    for (int off = 1; off < 1024; off <<= 1) {
        int add = (t >= off) ? tile[t - off] : 0;
        __syncthreads();
        tile[t] += add;
        __syncthreads();
    }
    if (t < nb) partials[t] = (t == 0) ? 0 : tile[t - 1];
    if (t == 0) row_ptr[0] = 0;
}

// Phase C: add block offsets
__global__ void scanC_kernel(const int* __restrict__ partials, int* __restrict__ row_ptr, int n) {
    int i = blockIdx.x * blockDim.x + threadIdx.x;
    if (i < n) row_ptr[i + 1] += partials[i >> 10];
}

__global__ void scatter_kernel(const int* __restrict__ rows, const int* __restrict__ cols,
                               const float* __restrict__ vals, const int* __restrict__ row_ptr,
                               int* __restrict__ fill, int2* __restrict__ edges, int E) {
    int stride = gridDim.x * blockDim.x;
    for (int e = blockIdx.x * blockDim.x + threadIdx.x; e < E; e += stride) {
        int r = rows[e];
        int pos = row_ptr[r] + atomicAdd(&fill[r], 1);
        edges[pos] = make_int2(cols[e], __float_as_int(vals[e]));
    }
}

// ---------------- GEMM: t0 = x @ W, stored fp16  (x:[N,128], W:[128,128]) ----------------
// W staged fp16 in LDS (32 KB -> 5 blocks/CU LDS-limit). x loads software-pipelined:
// chunk k+4's 8 broadcast float4 loads issued before chunk k's FMAs.

#define GEMM_ROWS 64

__global__ __launch_bounds__(256) void gemm_kernel(const float* __restrict__ x,
                                                   const float* __restrict__ w,
                                                   __half* __restrict__ out, int n) {
    __shared__ __half2 wl[CCH * 64];  // [k][col_pair], 32 KB
    for (int i = threadIdx.x; i < CCH * 64 / 2; i += 256) {
        float4 v = ((const float4*)w)[i];
        wl[2 * i]     = __float22half2_rn(make_float2(v.x, v.y));
        wl[2 * i + 1] = __float22half2_rn(make_float2(v.z, v.w));
    }
    __syncthreads();

    int tc = threadIdx.x & 31;   // col group: cols tc*4 .. tc*4+3
    int tr = threadIdx.x >> 5;   // row group 0..7
    int rbase = blockIdx.x * GEMM_ROWS + tr * 8;
    int nr = n - rbase;
    if (nr > 8) nr = 8;
    if (nr <= 0) nr = 0;

    float acc[8][4] = {};
    const float* xp = x + (size_t)rbase * CCH;

    float4 xc[8];
#pragma unroll
    for (int j = 0; j < 8; ++j)
        xc[j] = (j < nr) ? *(const float4*)(xp + (size_t)j * CCH)
                         : make_float4(0.f, 0.f, 0.f, 0.f);

    for (int k = 0; k < CCH; k += 4) {
        float4 xn[8];
        if (k + 4 < CCH) {
#pragma unroll
            for (int j = 0; j < 8; ++j)
                xn[j] = (j < nr) ? *(const float4*)(xp + (size_t)j * CCH + k + 4)
                                 : make_float4(0.f, 0.f, 0.f, 0.f);
        }
#pragma unroll
        for (int kk = 0; kk < 4; ++kk) {
            __half2 w01 = wl[(k + kk) * 64 + tc * 2];
            __half2 w23 = wl[(k + kk) * 64 + tc * 2 + 1];
            float2 f01 = __half22float2(w01);
            float2 f23 = __half22float2(w23);
#pragma unroll
            for (int j = 0; j < 8; ++j) {
                float xs = (kk == 0) ? xc[j].x : (kk == 1) ? xc[j].y : (kk == 2) ? xc[j].z : xc[j].w;
                acc[j][0] += xs * f01.x;
                acc[j][1] += xs * f01.y;
                acc[j][2] += xs * f23.x;
                acc[j][3] += xs * f23.y;
            }
        }
        if (k + 4 < CCH) {
#pragma unroll
            for (int j = 0; j < 8; ++j) xc[j] = xn[j];
        }
    }
#pragma unroll
    for (int j = 0; j < 8; ++j)
        if (j < nr) {
            __half2* orow = (__half2*)(out + (size_t)(rbase + j) * CCH + tc * 4);
            orow[0] = __float22half2_rn(make_float2(acc[j][0], acc[j][1]));
            orow[1] = __float22half2_rn(make_float2(acc[j][2], acc[j][3]));
        }
}

// ---------------- SpMM (fp16 src): dst[row] = (1/16) * sum_e val_e * src[col_e] ----------
// FINAL=1: dst = identity + FINAL_SCALE * sum (fp32, to d_out)
// 4 rows per wave, lockstep masked unroll-4 -> 16 outstanding gathers per wave;
// edge-descriptor loads pipelined one chunk ahead.

#define SROWS 4

template <int FINAL>
__global__ __launch_bounds__(256) void spmm_kernel(const int* __restrict__ row_ptr,
                                                   const int2* __restrict__ edges,
                                                   const __half2* __restrict__ src,
                                                   __half2* __restrict__ dsth,
                                                   float* __restrict__ dstf,
                                                   const float* __restrict__ identity,
                                                   int n) {
    int lane = threadIdx.x & 63;
    int wid = (blockIdx.x * blockDim.x + threadIdx.x) >> 6;
    int r0 = wid * SROWS;
    if (r0 >= n) return;

    int s[SROWS], e[SROWS];
#pragma unroll
    for (int j = 0; j < SROWS; ++j) {
        int r = r0 + j;
        bool ok = r < n;
        s[j] = ok ? row_ptr[r] : 0;
        e[j] = ok ? row_ptr[r + 1] : 0;
    }
    int chunks = 0;
#pragma unroll
    for (int j = 0; j < SROWS; ++j) {
        int c = (e[j] - s[j] + 3) >> 2;
        chunks = c > chunks ? c : chunks;
    }

    float2 acc[SROWS];
#pragma unroll
    for (int j = 0; j < SROWS; ++j) acc[j] = make_float2(0.f, 0.f);

    int2 edc[SROWS][4];
#pragma unroll
    for (int j = 0; j < SROWS; ++j)
#pragma unroll
        for (int t = 0; t < 4; ++t) {
            int i = s[j] + t;
            bool ok = i < e[j];
            edc[j][t] = edges[ok ? i : 0];
            if (!ok) edc[j][t].y = 0;
        }

    for (int it = 0; it < chunks; ++it) {
        int2 edn[SROWS][4];
        if (it + 1 < chunks) {
#pragma unroll
            for (int j = 0; j < SROWS; ++j)
#pragma unroll
                for (int t = 0; t < 4; ++t) {
                    int i = s[j] + (it + 1) * 4 + t;
                    bool ok = i < e[j];
                    edn[j][t] = edges[ok ? i : 0];
                    if (!ok) edn[j][t].y = 0;
                }
        }
        __half2 g[SROWS][4];
#pragma unroll
        for (int j = 0; j < SROWS; ++j)
#pragma unroll
            for (int t = 0; t < 4; ++t)
                g[j][t] = src[(size_t)edc[j][t].x * 64 + lane];
#pragma unroll
        for (int j = 0; j < SROWS; ++j)
#pragma unroll
            for (int t = 0; t < 4; ++t) {
                float v = __int_as_float(edc[j][t].y);
                float2 f = __half22float2(g[j][t]);
                acc[j].x += v * f.x;
                acc[j].y += v * f.y;
            }
        if (it + 1 < chunks) {
#pragma unroll
            for (int j = 0; j < SROWS; ++j)
#pragma unroll
                for (int t = 0; t < 4; ++t) edc[j][t] = edn[j][t];
        }
    }

    if (FINAL) {
#pragma unroll
        for (int j = 0; j < SROWS; ++j) {
            int r = r0 + j;
            if (r < n) {
                float2 iv = *(const float2*)(identity + (size_t)r * CCH + 2 * lane);
                *(float2*)(dstf + (size_t)r * CCH + 2 * lane) =
                    make_float2(iv.x + acc[j].x * FINAL_SCALE, iv.y + acc[j].y * FINAL_SCALE);
            }
        }
    } else {
#pragma unroll
        for (int j = 0; j < SROWS; ++j) {
            int r = r0 + j;
            if (r < n)
                dsth[(size_t)r * 64 + lane] =
                    __float22half2_rn(make_float2(acc[j].x * 0.0625f, acc[j].y * 0.0625f));
        }
    }
}

// ---------------- launch ----------------

static inline size_t align256(size_t x) { return (x + 255) & ~(size_t)255; }

extern "C" void kernel_launch(void* const* d_in, const int* in_sizes, int n_in,
                              void* d_out, int out_size, void* d_ws, size_t ws_size,
                              hipStream_t stream) {
    const float* x = (const float*)d_in[0];
    const float* w = (const float*)d_in[1];
    const float* lap_vals = (const float*)d_in[2];
    const int* lap_rows = (const int*)d_in[3];
    const int* lap_cols = (const int*)d_in[4];

    const int N = in_sizes[0] / CCH;   // 100000
    const int E = in_sizes[2];         // 3200000
    const int NB = (N + 1023) / 1024;  // scan blocks

    // workspace layout
    char* ws = (char*)d_ws;
    size_t off = 0;
    __half* bufA = (__half*)(ws + off); off = align256(off + (size_t)N * CCH * sizeof(__half));
    __half* bufB = (__half*)(ws + off); off = align256(off + (size_t)N * CCH * sizeof(__half));
    int2* edges = (int2*)(ws + off);    off = align256(off + (size_t)E * sizeof(int2));
    int* row_ptr = (int*)(ws + off);    off = align256(off + (size_t)(N + 1) * sizeof(int));
    int* counts = (int*)(ws + off);     off = align256(off + (size_t)N * sizeof(int));
    int* fill = (int*)(ws + off);       off = align256(off + (size_t)N * sizeof(int));
    int* partials = (int*)(ws + off);   off = align256(off + (size_t)NB * sizeof(int));
    (void)ws_size;

    float* out = (float*)d_out;

    hipMemsetAsync(counts, 0, (size_t)N * sizeof(int), stream);
    hipMemsetAsync(fill, 0, (size_t)N * sizeof(int), stream);

    // CSR build
    hist_kernel<<<2048, 256, 0, stream>>>(lap_rows, counts, E);
    scanA_kernel<<<NB, 1024, 0, stream>>>(counts, row_ptr, partials, N);
    scanB_kernel<<<1, 1024, 0, stream>>>(partials, row_ptr, NB);
    scanC_kernel<<<(N + 255) / 256, 256, 0, stream>>>(partials, row_ptr, N);
    scatter_kernel<<<2048, 256, 0, stream>>>(lap_rows, lap_cols, lap_vals, row_ptr, fill, edges, E);

    // GEMM -> bufA (fp16 t0)
    gemm_kernel<<<(N + GEMM_ROWS - 1) / GEMM_ROWS, 256, 0, stream>>>(x, w, bufA, N);

    // steps 1..7 fp16 ping-pong (each scaled 1/16), step 8 fp32 -> d_out (+identity, x16^7)
    int waves_needed = (N + SROWS - 1) / SROWS;
    int spmm_blocks = (waves_needed + 3) / 4;  // 4 waves per 256-thread block
    const __half2* src = (const __half2*)bufA;
    __half2* dst = (__half2*)bufB;
    for (int step = 1; step <= 7; ++step) {
        spmm_kernel<0><<<spmm_blocks, 256, 0, stream>>>(row_ptr, edges, src, dst, nullptr, nullptr, N);
        __half2* t = (__half2*)src;
        src = (const __half2*)dst;
        dst = t;
    }
    // after 7 steps t7 is in bufB (src points at it)
    spmm_kernel<1><<<spmm_blocks, 256, 0, stream>>>(row_ptr, edges, src, nullptr, out, x, N);
}

// Round 5
// 1348.503 us; speedup vs baseline: 1.4383x; 1.4383x over previous
//
#include <hip/hip_runtime.h>
#include <hip/hip_bf16.h>
#include <hip/hip_fp16.h>
#include <stdint.h>

#define CCH 128  // channels
#define FINAL_SCALE 268435456.0f  // 16^7: undo 7 steps of 1/16 scaling (step 8 unscaled)

// ---------------- CSR build ----------------

__global__ void hist_kernel(const int* __restrict__ rows, int* __restrict__ counts, int E) {
    int stride = gridDim.x * blockDim.x;
    for (int e = blockIdx.x * blockDim.x + threadIdx.x; e < E; e += stride)
        atomicAdd(&counts[rows[e]], 1);
}

// Phase A: per-block (1024) inclusive scan -> row_ptr[i+1] (tile-local), block sum -> partials
__global__ __launch_bounds__(1024) void scanA_kernel(const int* __restrict__ counts,
                                                     int* __restrict__ row_ptr,
                                                     int* __restrict__ partials, int n) {
    __shared__ int tile[1024];
    int t = threadIdx.x;
    int i = blockIdx.x * 1024 + t;
    tile[t] = (i < n) ? counts[i] : 0;
    __syncthreads();
    for (int off = 1; off < 1024; off <<= 1) {
        int add = (t >= off) ? tile[t - off] : 0;
        __syncthreads();
        tile[t] += add;
        __syncthreads();
    }
    if (i < n) row_ptr[i + 1] = tile[t];
    if (t == 1023) partials[blockIdx.x] = tile[1023];
}

// Phase B: single block scans partials (nb <= 1024) in place -> exclusive offsets
__global__ __launch_bounds__(1024) void scanB_kernel(int* __restrict__ partials,
                                                     int* __restrict__ row_ptr, int nb) {
    __shared__ int tile[1024];
    int t = threadIdx.x;
    tile[t] = (t < nb) ? partials[t] : 0;
    __syncthreads();
    for (int off = 1; off < 1024; off <<= 1) {
        int add = (t >= off) ? tile[t - off] : 0;
        __syncthreads();
        tile[t] += add;
        __syncthreads();
    }
    if (t < nb) partials[t] = (t == 0) ? 0 : tile[t - 1];
    if (t == 0) row_ptr[0] = 0;
}

// Phase C: add block offsets
__global__ void scanC_kernel(const int* __restrict__ partials, int* __restrict__ row_ptr, int n) {
    int i = blockIdx.x * blockDim.x + threadIdx.x;
    if (i < n) row_ptr[i + 1] += partials[i >> 10];
}

__global__ void scatter_kernel(const int* __restrict__ rows, const int* __restrict__ cols,
                               const float* __restrict__ vals, const int* __restrict__ row_ptr,
                               int* __restrict__ fill, int2* __restrict__ edges, int E) {
    int stride = gridDim.x * blockDim.x;
    for (int e = blockIdx.x * blockDim.x + threadIdx.x; e < E; e += stride) {
        int r = rows[e];
        int pos = row_ptr[r] + atomicAdd(&fill[r], 1);
        edges[pos] = make_int2(cols[e], __float_as_int(vals[e]));
    }
}

// ---------------- GEMM: t0 = x @ W, stored fp16  (x:[N,128], W:[128,128]) ----------------
// W staged fp16 in LDS (32 KB). x loads software-pipelined one 4-k chunk ahead.

#define GEMM_ROWS 64

__global__ __launch_bounds__(256) void gemm_kernel(const float* __restrict__ x,
                                                   const float* __restrict__ w,
                                                   __half* __restrict__ out, int n) {
    __shared__ __half2 wl[CCH * 64];  // [k][col_pair], 32 KB
    for (int i = threadIdx.x; i < CCH * 64 / 2; i += 256) {
        float4 v = ((const float4*)w)[i];
        wl[2 * i]     = __float22half2_rn(make_float2(v.x, v.y));
        wl[2 * i + 1] = __float22half2_rn(make_float2(v.z, v.w));
    }
    __syncthreads();

    int tc = threadIdx.x & 31;   // col group: cols tc*4 .. tc*4+3
    int tr = threadIdx.x >> 5;   // row group 0..7
    int rbase = blockIdx.x * GEMM_ROWS + tr * 8;
    int nr = n - rbase;
    if (nr > 8) nr = 8;
    if (nr <= 0) nr = 0;

    float acc[8][4] = {};
    const float* xp = x + (size_t)rbase * CCH;

    float4 xc[8];
#pragma unroll
    for (int j = 0; j < 8; ++j)
        xc[j] = (j < nr) ? *(const float4*)(xp + (size_t)j * CCH)
                         : make_float4(0.f, 0.f, 0.f, 0.f);

    for (int k = 0; k < CCH; k += 4) {
        float4 xn[8];
        if (k + 4 < CCH) {
#pragma unroll
            for (int j = 0; j < 8; ++j)
                xn[j] = (j < nr) ? *(const float4*)(xp + (size_t)j * CCH + k + 4)
                                 : make_float4(0.f, 0.f, 0.f, 0.f);
        }
#pragma unroll
        for (int kk = 0; kk < 4; ++kk) {
            __half2 w01 = wl[(k + kk) * 64 + tc * 2];
            __half2 w23 = wl[(k + kk) * 64 + tc * 2 + 1];
            float2 f01 = __half22float2(w01);
            float2 f23 = __half22float2(w23);
#pragma unroll
            for (int j = 0; j < 8; ++j) {
                float xs = (kk == 0) ? xc[j].x : (kk == 1) ? xc[j].y : (kk == 2) ? xc[j].z : xc[j].w;
                acc[j][0] += xs * f01.x;
                acc[j][1] += xs * f01.y;
                acc[j][2] += xs * f23.x;
                acc[j][3] += xs * f23.y;
            }
        }
        if (k + 4 < CCH) {
#pragma unroll
            for (int j = 0; j < 8; ++j) xc[j] = xn[j];
        }
    }
#pragma unroll
    for (int j = 0; j < 8; ++j)
        if (j < nr) {
            __half2* orow = (__half2*)(out + (size_t)(rbase + j) * CCH + tc * 4);
            orow[0] = __float22half2_rn(make_float2(acc[j][0], acc[j][1]));
            orow[1] = __float22half2_rn(make_float2(acc[j][2], acc[j][3]));
        }
}

// ---------------- SpMM (fp16 src): dst[row] = (1/16) * sum_e val_e * src[col_e] ----------
// One row per wave; 4 groups of 16 lanes each process their own edge with a
// dwordx4 gather (16 lanes x 16 B = one 256 B fp16 row) -> 4 edges per VMEM
// instruction, 16 edges in flight per wave. Cross-group shuffle-reduce at end.
// FINAL=1: dst = identity + FINAL_SCALE * sum (fp32, to d_out)

template <int FINAL>
__global__ __launch_bounds__(256) void spmm_kernel(const int* __restrict__ row_ptr,
                                                   const int2* __restrict__ edges,
                                                   const __half* __restrict__ src,
                                                   __half* __restrict__ dsth,
                                                   float* __restrict__ dstf,
                                                   const float* __restrict__ identity,
                                                   int n) {
    int lane = threadIdx.x & 63;
    int row = (blockIdx.x * blockDim.x + threadIdx.x) >> 6;
    if (row >= n) return;
    int g = lane >> 4;    // group 0..3
    int gl = lane & 15;   // lane within group; covers channels gl*8 .. gl*8+7

    int s = row_ptr[row];
    int e = row_ptr[row + 1];

    float acc[8] = {};

    for (int base = s; base < e; base += 16) {
        int2 ed[4];
        float4 gv[4];
#pragma unroll
        for (int t = 0; t < 4; ++t) {
            int idx = base + g * 4 + t;
            bool ok = idx < e;
            ed[t] = edges[ok ? idx : s];
            if (!ok) ed[t].y = 0;  // val = 0.0f
        }
#pragma unroll
        for (int t = 0; t < 4; ++t)
            gv[t] = *(const float4*)(src + (size_t)ed[t].x * CCH + gl * 8);
#pragma unroll
        for (int t = 0; t < 4; ++t) {
            float v = __int_as_float(ed[t].y);
            const __half* h = (const __half*)&gv[t];
#pragma unroll
            for (int j = 0; j < 8; ++j)
                acc[j] += v * __half2float(h[j]);  // v_fma_mix
        }
    }

    // reduce partial sums across the 4 groups (all lanes end with full sum)
#pragma unroll
    for (int j = 0; j < 8; ++j) {
        acc[j] += __shfl_xor(acc[j], 16, 64);
        acc[j] += __shfl_xor(acc[j], 32, 64);
    }

    if (FINAL) {
        // g0 stores channels gl*8..+3, g1 stores gl*8+4..+7 (32 lanes, 512 B/row)
        if (g == 0) {
            const float* iv = identity + (size_t)row * CCH + gl * 8;
            float4 o;
            o.x = iv[0] + acc[0] * FINAL_SCALE;
            o.y = iv[1] + acc[1] * FINAL_SCALE;
            o.z = iv[2] + acc[2] * FINAL_SCALE;
            o.w = iv[3] + acc[3] * FINAL_SCALE;
            *(float4*)(dstf + (size_t)row * CCH + gl * 8) = o;
        } else if (g == 1) {
            const float* iv = identity + (size_t)row * CCH + gl * 8 + 4;
            float4 o;
            o.x = iv[0] + acc[4] * FINAL_SCALE;
            o.y = iv[1] + acc[5] * FINAL_SCALE;
            o.z = iv[2] + acc[6] * FINAL_SCALE;
            o.w = iv[3] + acc[7] * FINAL_SCALE;
            *(float4*)(dstf + (size_t)row * CCH + gl * 8 + 4) = o;
        }
    } else {
        if (g == 0) {
            __half2 h[4];
            h[0] = __float22half2_rn(make_float2(acc[0] * 0.0625f, acc[1] * 0.0625f));
            h[1] = __float22half2_rn(make_float2(acc[2] * 0.0625f, acc[3] * 0.0625f));
            h[2] = __float22half2_rn(make_float2(acc[4] * 0.0625f, acc[5] * 0.0625f));
            h[3] = __float22half2_rn(make_float2(acc[6] * 0.0625f, acc[7] * 0.0625f));
            *(float4*)(dsth + (size_t)row * CCH + gl * 8) = *(float4*)h;
        }
    }
}

// ---------------- launch ----------------

static inline size_t align256(size_t x) { return (x + 255) & ~(size_t)255; }

extern "C" void kernel_launch(void* const* d_in, const int* in_sizes, int n_in,
                              void* d_out, int out_size, void* d_ws, size_t ws_size,
                              hipStream_t stream) {
    const float* x = (const float*)d_in[0];
    const float* w = (const float*)d_in[1];
    const float* lap_vals = (const float*)d_in[2];
    const int* lap_rows = (const int*)d_in[3];
    const int* lap_cols = (const int*)d_in[4];

    const int N = in_sizes[0] / CCH;   // 100000
    const int E = in_sizes[2];         // 3200000
    const int NB = (N + 1023) / 1024;  // scan blocks

    // workspace layout
    char* ws = (char*)d_ws;
    size_t off = 0;
    __half* bufA = (__half*)(ws + off); off = align256(off + (size_t)N * CCH * sizeof(__half));
    __half* bufB = (__half*)(ws + off); off = align256(off + (size_t)N * CCH * sizeof(__half));
    int2* edges = (int2*)(ws + off);    off = align256(off + (size_t)E * sizeof(int2));
    int* row_ptr = (int*)(ws + off);    off = align256(off + (size_t)(N + 1) * sizeof(int));
    int* counts = (int*)(ws + off);     off = align256(off + (size_t)N * sizeof(int));
    int* fill = (int*)(ws + off);       off = align256(off + (size_t)N * sizeof(int));
    int* partials = (int*)(ws + off);   off = align256(off + (size_t)NB * sizeof(int));
    (void)ws_size;

    float* out = (float*)d_out;

    hipMemsetAsync(counts, 0, (size_t)N * sizeof(int), stream);
    hipMemsetAsync(fill, 0, (size_t)N * sizeof(int), stream);

    // CSR build
    hist_kernel<<<2048, 256, 0, stream>>>(lap_rows, counts, E);
    scanA_kernel<<<NB, 1024, 0, stream>>>(counts, row_ptr, partials, N);
    scanB_kernel<<<1, 1024, 0, stream>>>(partials, row_ptr, NB);
    scanC_kernel<<<(N + 255) / 256, 256, 0, stream>>>(partials, row_ptr, N);
    scatter_kernel<<<2048, 256, 0, stream>>>(lap_rows, lap_cols, lap_vals, row_ptr, fill, edges, E);

    // GEMM -> bufA (fp16 t0)
    gemm_kernel<<<(N + GEMM_ROWS - 1) / GEMM_ROWS, 256, 0, stream>>>(x, w, bufA, N);

    // steps 1..7 fp16 ping-pong (each scaled 1/16), step 8 fp32 -> d_out (+identity, x16^7)
    int spmm_blocks = (N + 3) / 4;  // 1 row per wave, 4 waves per 256-thread block
    const __half* src = bufA;
    __half* dst = bufB;
    for (int step = 1; step <= 7; ++step) {
        spmm_kernel<0><<<spmm_blocks, 256, 0, stream>>>(row_ptr, edges, src, dst, nullptr, nullptr, N);
        __half* t = (__half*)src;
        src = dst;
        dst = t;
    }
    // after 7 steps t7 is in bufB (src points at it)
    spmm_kernel<1><<<spmm_blocks, 256, 0, stream>>>(row_ptr, edges, src, nullptr, out, x, N);
}